// Round 3
// baseline (100.877 us; speedup 1.0000x reference)
//
#include <hip/hip_runtime.h>
#include <math.h>

#define Hdim    256                    // embedding dim
#define NMAX    8192
#define APAD    64                     // anchor-tile size; class buckets padded to 64
#define NPADMAX (NMAX + 6 * APAD)
#define WLMAX   144                    // static sim grid: >= 8192/64 + 6 = 134 tiles
#define BIGV    1e9f
#define MARGIN  0.5f

typedef __attribute__((ext_vector_type(8))) short bf16x8;   // MFMA A/B frag
typedef __attribute__((ext_vector_type(4))) float f32x4;    // MFMA C/D frag

struct WS {
    unsigned short ebf[NMAX][Hdim];    // normalized bf16 rows at ORIGINAL row positions
    int idx[NPADMAX];                  // class-bucketed original-row index list (padded to 64)
    int S[8];                          // S[1..6] bucket starts, S[7] = padded end
    int n[8];                          // real bucket counts
    int wl_a[WLMAX];                   // worklist: anchor base (bucketed coords)
    int wl_c[WLMAX];                   // worklist: class
    int T;                             // worklist length
    unsigned done;                     // block completion counter
    float wsum;                        // triplet loss sum
    int   wcnt;                        // triplet count
};

__device__ inline unsigned short f2bf(float f) {    // fp32 -> bf16 RNE
    unsigned u = __float_as_uint(f);
    return (unsigned short)((u + 0x7fffu + ((u >> 16) & 1u)) >> 16);
}

// ---- K1 fused: block 0 = planning via ATOMIC-FREE counting sort (per-wave ballot
//      counts -> tid0 prefix -> per-wave exclusive-region scatter, ~2k cycles);
//      blocks 1..512 = per-row L2-normalize -> bf16 at ORIGINAL position.
//      The two roles have no data dependency (norm keys off lab[] directly), so the
//      plan block hides entirely under the norm blocks. (Round-2's 16k same-address
//      LDS atomics serialized ~1/cyc -> ~6-7us; this replaces them with popc math.)
__global__ __launch_bounds__(1024) void prep_kernel(const float* __restrict__ in,
                                                    const int* __restrict__ lab,
                                                    WS* ws, int N) {
    if (blockIdx.x == 0) {
        __shared__ int cnt[16][8];     // per-wave class counts
        __shared__ int off[16][8];     // per-wave exclusive scatter bases
        __shared__ int S[8], h[8], ntp[8];
        const int tid  = threadIdx.x;
        const int lane = tid & 63;
        const int wv   = tid >> 6;

        int l[8];                      // preload: 8 labels/thread, loads pipelined
        #pragma unroll
        for (int k = 0; k < 8; ++k) {
            int i = tid + (k << 10);
            l[k] = (i < N) ? lab[i] : 0;
        }

        // pass 1: per-wave counts via ballots (no atomics)
        int cw[7] = {0, 0, 0, 0, 0, 0, 0};
        #pragma unroll
        for (int k = 0; k < 8; ++k)
            #pragma unroll
            for (int c = 1; c <= 6; ++c)
                cw[c] += (int)__popcll(__ballot(l[k] == c));
        if (lane == 0)
            #pragma unroll
            for (int c = 1; c <= 6; ++c) cnt[wv][c] = cw[c];
        __syncthreads();

        // tid 0: totals, layout, worklist geometry, per-wave exclusive offsets (~200 ops)
        if (tid == 0) {
            int acc = 0, tt = 0;
            for (int c = 1; c <= 6; ++c) {
                int hc = 0;
                for (int w = 0; w < 16; ++w) hc += cnt[w][c];
                h[c]   = hc;
                S[c]   = acc; acc += ((hc + APAD - 1) / APAD) * APAD;
                ntp[c] = tt;  tt  += (hc + APAD - 1) / APAD;
            }
            S[0] = 0; S[7] = acc; ntp[0] = 0; ntp[7] = tt;
            ws->T = tt;
            ws->done = 0u; ws->wsum = 0.f; ws->wcnt = 0;
            ws->n[0] = 0; ws->n[7] = 0;
            for (int c = 1; c <= 6; ++c) ws->n[c] = h[c];
            for (int c = 0; c < 8; ++c) ws->S[c] = S[c];
            for (int c = 1; c <= 6; ++c) {
                int a = S[c];
                for (int w = 0; w < 16; ++w) { off[w][c] = a; a += cnt[w][c]; }
            }
        }
        __syncthreads();

        // worklist, parallel over tiles
        if (tid < ntp[7]) {
            int c = 1;
            while (tid >= ntp[c + 1]) ++c;
            ws->wl_a[tid] = S[c] + (tid - ntp[c]) * APAD;
            ws->wl_c[tid] = c;
        }
        // pad slots -> row 0 (keeps sim addresses in-bounds; masked positionally later)
        if (tid < 6 * APAD) {
            int c = (tid >> 6) + 1;
            int s = S[c] + h[c] + (tid & 63);
            if (s < S[c + 1]) ws->idx[s] = 0;
        }

        // pass 2: scatter into per-wave exclusive regions — pure ballot/popc, no atomics.
        // Result is order-invariant (sim takes min/max over the set).
        int oc[7];
        #pragma unroll
        for (int c = 1; c <= 6; ++c) oc[c] = off[wv][c];
        const unsigned long long below = (1ull << lane) - 1ull;
        #pragma unroll
        for (int k = 0; k < 8; ++k) {
            int i = tid + (k << 10);
            #pragma unroll
            for (int c = 1; c <= 6; ++c) {
                unsigned long long m = __ballot(l[k] == c);
                if (l[k] == c)
                    ws->idx[oc[c] + (int)__popcll(m & below)] = i;
                oc[c] += (int)__popcll(m);       // wave-uniform running offset
            }
        }
    } else {
        const int row  = (blockIdx.x - 1) * 16 + (threadIdx.x >> 6);
        const int lane = threadIdx.x & 63;
        if (row >= N) return;
        const int l = lab[row];                // wave-uniform
        if (l < 1 || l > 6) return;            // class not in any confused pair: never read
        float4 v = ((const float4*)(in + (size_t)row * Hdim))[lane];
        float ss = v.x*v.x + v.y*v.y + v.z*v.z + v.w*v.w;
        #pragma unroll
        for (int off2 = 32; off2 >= 1; off2 >>= 1) ss += __shfl_xor(ss, off2);
        float sc = 1.0f / fmaxf(sqrtf(ss), 1e-12f);
        ushort4 o;
        o.x = f2bf(v.x * sc); o.y = f2bf(v.y * sc);
        o.z = f2bf(v.z * sc); o.w = f2bf(v.w * sc);
        ((ushort4*)(&ws->ebf[row][0]))[lane] = o;
    }
}

// ---- K2: one block = one 64-ANCHOR tile (halves aggregate L2 B-traffic vs 32),
//          full j-sweep via idx indirection; LDS combine; ~3 atomics/block ----
__global__ __launch_bounds__(256) void sim_kernel(WS* ws, float* __restrict__ out) {
    const int wave = threadIdx.x >> 6;
    const int lane = threadIdx.x & 63;
    const int col  = lane & 15;            // C col = j index
    const int quad = lane >> 4;            // C row group
    const int tileIdx = blockIdx.x;

    __shared__ float lds_hp[4][64], lds_hn[4][64];

    if (tileIdx < ws->T) {
        const int aBase = ws->wl_a[tileIdx];
        const int c     = ws->wl_c[tileIdx];
        const int p     = ((c - 1) ^ 1) + 1;          // confused partner: (1,2)(3,4)(5,6)
        const int posS = ws->S[c], posRealE = posS + ws->n[c];
        const int negS = ws->S[p], negRealE = negS + ws->n[p];
        const int nPosT = (ws->S[c + 1] - posS) >> 4; // padded ends are S[x+1]; 64 % 16 == 0
        const int nNegT = (ws->S[p + 1] - negS) >> 4;
        const int nTT   = nPosT + nNegT;
        const bool hasPN = (ws->n[c] >= 2) && (ws->n[p] >= 1);

        const unsigned short* ebf = &ws->ebf[0][0];
        const int* __restrict__ idx = ws->idx;

        bf16x8 afrag[4][8];                            // A frags: [g=anchor group][k]
        #pragma unroll
        for (int g = 0; g < 4; ++g) {
            int ar = idx[aBase + g * 16 + col];
            const unsigned short* rp = ebf + (size_t)ar * Hdim + quad * 8;
            #pragma unroll
            for (int ks = 0; ks < 8; ++ks)
                afrag[g][ks] = *(const bf16x8*)(rp + ks * 32);
        }

        float runMin[4][4], runMax[4][4];
        #pragma unroll
        for (int g = 0; g < 4; ++g)
            #pragma unroll
            for (int r = 0; r < 4; ++r) { runMin[g][r] = BIGV; runMax[g][r] = -BIGV; }

        auto j0Of = [&](int t) -> int {
            return (t < nPosT) ? (posS + (t << 4)) : (negS + ((t - nPosT) << 4));
        };
        bf16x8 b0[8], b1[8];
        auto loadB = [&](bf16x8 (&bf)[8], int t) {
            int jr = idx[j0Of(t) + col];
            const unsigned short* rp = ebf + (size_t)jr * Hdim + quad * 8;
            #pragma unroll
            for (int ks = 0; ks < 8; ++ks)
                bf[ks] = *(const bf16x8*)(rp + ks * 32);
        };
        auto computeT = [&](bf16x8 (&bf)[8], int t) {
            int j0 = j0Of(t);
            bool isPos = t < nPosT;                    // wave-uniform
            int realE  = isPos ? posRealE : negRealE;
            bool valid = (j0 + col) < realE;           // positional mask, 1 v_cmp/tile
            #pragma unroll
            for (int g = 0; g < 4; ++g) {
                f32x4 acc = {0.f, 0.f, 0.f, 0.f};
                #pragma unroll
                for (int ks = 0; ks < 8; ++ks)
                    acc = __builtin_amdgcn_mfma_f32_16x16x32_bf16(afrag[g][ks], bf[ks], acc, 0, 0, 0);
                if (isPos) {                           // self-sim is max => min unaffected (n>=2 gated)
                    #pragma unroll
                    for (int r = 0; r < 4; ++r)
                        runMin[g][r] = fminf(runMin[g][r], valid ? acc[r] : BIGV);
                } else {
                    #pragma unroll
                    for (int r = 0; r < 4; ++r)
                        runMax[g][r] = fmaxf(runMax[g][r], valid ? acc[r] : -BIGV);
                }
            }
        };

        // 4 waves stride the j-tile list; register double-buffered
        int nIter = (nTT > wave) ? ((nTT - wave + 3) >> 2) : 0;
        int t = wave, i = 0;
        if (nIter > 0) loadB(b0, t);
        while (i + 2 <= nIter) {
            loadB(b1, t + 4);
            computeT(b0, t);
            if (i + 2 < nIter) loadB(b0, t + 8);
            computeT(b1, t + 4);
            t += 8; i += 2;
        }
        if (i < nIter) computeT(b0, t);

        // reduce across 16 cols; col==0 lanes stash per-wave results in LDS
        #pragma unroll
        for (int g = 0; g < 4; ++g)
            #pragma unroll
            for (int r = 0; r < 4; ++r) {
                float mn = runMin[g][r], mx = runMax[g][r];
                #pragma unroll
                for (int off = 1; off < 16; off <<= 1) {
                    mn = fminf(mn, __shfl_xor(mn, off));
                    mx = fmaxf(mx, __shfl_xor(mx, off));
                }
                if (col == 0) {
                    int a = g * 16 + quad * 4 + r;
                    lds_hp[wave][a] = mn;
                    lds_hn[wave][a] = mx;
                }
            }
        __syncthreads();

        // wave 0: combine 4 waves; all 64 lanes = 64 anchors of this tile
        if (wave == 0) {
            float hp = fminf(fminf(lds_hp[0][lane], lds_hp[1][lane]),
                             fminf(lds_hp[2][lane], lds_hp[3][lane]));
            float hn = fmaxf(fmaxf(lds_hn[0][lane], lds_hn[1][lane]),
                             fmaxf(lds_hn[2][lane], lds_hn[3][lane]));
            bool real = (aBase + lane) < posRealE;
            float contrib = 0.f; int cc = 0;
            if (real && hasPN) {
                float tr = MARGIN + hn - hp;
                contrib = (tr > 0.f) ? tr : 0.f;
                cc = 1;
            }
            #pragma unroll
            for (int off = 32; off >= 1; off >>= 1) {
                contrib += __shfl_xor(contrib, off);
                cc      += __shfl_xor(cc, off);
            }
            if (lane == 0) {
                atomicAdd(&ws->wsum, contrib);
                atomicAdd(&ws->wcnt, cc);
            }
        }
    }

    // completion: same thread that issued data atomics drains them (s_waitcnt) first;
    // last block atomic-reads the totals. No threadfence / L2 writeback needed.
    if (threadIdx.x == 0) {
        __builtin_amdgcn_s_waitcnt(0);
        unsigned old = atomicAdd(&ws->done, 1u);
        if (old == (unsigned)(gridDim.x - 1)) {
            float s = atomicAdd(&ws->wsum, 0.0f);   // coherent atomic read
            int   n = atomicAdd(&ws->wcnt, 0);
            out[0] = (n > 0) ? s / (float)n : 0.f;
        }
    }
}

extern "C" void kernel_launch(void* const* d_in, const int* in_sizes, int n_in,
                              void* d_out, int out_size, void* d_ws, size_t ws_size,
                              hipStream_t stream) {
    const float* emb = (const float*)d_in[0];
    const int*   lab = (const int*)d_in[1];
    int N = in_sizes[1];                               // 8192
    WS* ws = (WS*)d_ws;

    prep_kernel<<<1 + (N + 15) / 16, 1024, 0, stream>>>(emb, lab, ws, N);
    sim_kernel<<<WLMAX, 256, 0, stream>>>(ws, (float*)d_out);
}

// Round 4
// 97.294 us; speedup vs baseline: 1.0368x; 1.0368x over previous
//
#include <hip/hip_runtime.h>
#include <math.h>

#define Hdim    256                    // embedding dim
#define NMAX    8192
#define APAD    32                     // anchor-tile size; class buckets padded to 32
#define NPADMAX (NMAX + 6 * APAD)
#define WLMAX   264                    // static sim grid: max 32-anchor tiles
#define BIGV    1e9f
#define MARGIN  0.5f

typedef __attribute__((ext_vector_type(8))) short bf16x8;   // MFMA A/B frag
typedef __attribute__((ext_vector_type(4))) float f32x4;    // MFMA C/D frag

struct WS {
    unsigned short ebf[NMAX][Hdim];    // normalized bf16 rows at ORIGINAL row positions
    int idx[NPADMAX];                  // class-bucketed original-row index list (padded to 32)
    int S[8];                          // S[1..6] bucket starts, S[7] = padded end
    int n[8];                          // real bucket counts
    int wl_a[WLMAX];                   // worklist: anchor base (bucketed coords)
    int wl_c[WLMAX];                   // worklist: class
    int T;                             // worklist length
    unsigned done;                     // block completion counter
    float wsum;                        // triplet loss sum
    int   wcnt;                        // triplet count
};

__device__ inline unsigned short f2bf(float f) {    // fp32 -> bf16 RNE
    unsigned u = __float_as_uint(f);
    return (unsigned short)((u + 0x7fffu + ((u >> 16) & 1u)) >> 16);
}

// ---- K1 fused: block 0 = planning via ATOMIC-FREE counting sort (per-wave ballot
//      counts -> tid0 prefix -> per-wave exclusive-region scatter, ~2k cycles);
//      blocks 1..512 = per-row L2-normalize -> bf16 at ORIGINAL position.
//      No data dependency between roles (norm keys off lab[] directly) -> plan block
//      hides entirely under the 512 norm blocks. (Round-2's 16k same-address LDS
//      atomics serialized ~1/cyc ~6us; round-3 proved this ballot form correct.)
__global__ __launch_bounds__(1024) void prep_kernel(const float* __restrict__ in,
                                                    const int* __restrict__ lab,
                                                    WS* ws, int N) {
    if (blockIdx.x == 0) {
        __shared__ int cnt[16][8];     // per-wave class counts
        __shared__ int off[16][8];     // per-wave exclusive scatter bases
        __shared__ int S[8], h[8], ntp[8];
        const int tid  = threadIdx.x;
        const int lane = tid & 63;
        const int wv   = tid >> 6;

        int l[8];                      // preload: 8 labels/thread, loads pipelined
        #pragma unroll
        for (int k = 0; k < 8; ++k) {
            int i = tid + (k << 10);
            l[k] = (i < N) ? lab[i] : 0;
        }

        // pass 1: per-wave counts via ballots (no atomics)
        int cw[7] = {0, 0, 0, 0, 0, 0, 0};
        #pragma unroll
        for (int k = 0; k < 8; ++k)
            #pragma unroll
            for (int c = 1; c <= 6; ++c)
                cw[c] += (int)__popcll(__ballot(l[k] == c));
        if (lane == 0)
            #pragma unroll
            for (int c = 1; c <= 6; ++c) cnt[wv][c] = cw[c];
        __syncthreads();

        // tid 0: totals, layout, worklist geometry, per-wave exclusive offsets (~200 ops)
        if (tid == 0) {
            int acc = 0, tt = 0;
            for (int c = 1; c <= 6; ++c) {
                int hc = 0;
                for (int w = 0; w < 16; ++w) hc += cnt[w][c];
                h[c]   = hc;
                S[c]   = acc; acc += ((hc + APAD - 1) / APAD) * APAD;
                ntp[c] = tt;  tt  += (hc + APAD - 1) / APAD;
            }
            S[0] = 0; S[7] = acc; ntp[0] = 0; ntp[7] = tt;
            ws->T = tt;
            ws->done = 0u; ws->wsum = 0.f; ws->wcnt = 0;
            ws->n[0] = 0; ws->n[7] = 0;
            for (int c = 1; c <= 6; ++c) ws->n[c] = h[c];
            for (int c = 0; c < 8; ++c) ws->S[c] = S[c];
            for (int c = 1; c <= 6; ++c) {
                int a = S[c];
                for (int w = 0; w < 16; ++w) { off[w][c] = a; a += cnt[w][c]; }
            }
        }
        __syncthreads();

        // worklist, parallel over tiles
        if (tid < ntp[7]) {
            int c = 1;
            while (tid >= ntp[c + 1]) ++c;
            ws->wl_a[tid] = S[c] + (tid - ntp[c]) * APAD;
            ws->wl_c[tid] = c;
        }
        // pad slots -> row 0 (keeps sim addresses in-bounds; masked positionally later)
        if (tid < 6 * APAD) {
            int c = tid / APAD + 1;
            int s = S[c] + h[c] + (tid % APAD);
            if (s < S[c + 1]) ws->idx[s] = 0;
        }

        // pass 2: scatter into per-wave exclusive regions — pure ballot/popc, no atomics.
        // Result is order-invariant (sim takes min/max over the set).
        int oc[7];
        #pragma unroll
        for (int c = 1; c <= 6; ++c) oc[c] = off[wv][c];
        const unsigned long long below = (1ull << lane) - 1ull;
        #pragma unroll
        for (int k = 0; k < 8; ++k) {
            int i = tid + (k << 10);
            #pragma unroll
            for (int c = 1; c <= 6; ++c) {
                unsigned long long m = __ballot(l[k] == c);
                if (l[k] == c)
                    ws->idx[oc[c] + (int)__popcll(m & below)] = i;
                oc[c] += (int)__popcll(m);       // wave-uniform running offset
            }
        }
    } else {
        const int row  = (blockIdx.x - 1) * 16 + (threadIdx.x >> 6);
        const int lane = threadIdx.x & 63;
        if (row >= N) return;
        const int l = lab[row];                // wave-uniform
        if (l < 1 || l > 6) return;            // class not in any confused pair: never read
        float4 v = ((const float4*)(in + (size_t)row * Hdim))[lane];
        float ss = v.x*v.x + v.y*v.y + v.z*v.z + v.w*v.w;
        #pragma unroll
        for (int off2 = 32; off2 >= 1; off2 >>= 1) ss += __shfl_xor(ss, off2);
        float sc = 1.0f / fmaxf(sqrtf(ss), 1e-12f);
        ushort4 o;
        o.x = f2bf(v.x * sc); o.y = f2bf(v.y * sc);
        o.z = f2bf(v.z * sc); o.w = f2bf(v.w * sc);
        ((ushort4*)(&ws->ebf[row][0]))[lane] = o;
    }
}

// ---- K2: one block = one 32-anchor tile (round-2 proven config: ~130 VGPR, 2 waves/
//          SIMD headroom; round-3's 64-anchor variant hit the 256-VGPR cliff and
//          regressed), full j-sweep via idx indirection; LDS combine; ~3 atomics ----
__global__ __launch_bounds__(256) void sim_kernel(WS* ws, float* __restrict__ out) {
    const int wave = threadIdx.x >> 6;
    const int lane = threadIdx.x & 63;
    const int col  = lane & 15;            // C col = j index
    const int quad = lane >> 4;            // C row group
    const int tileIdx = blockIdx.x;

    __shared__ float lds_hp[4][32], lds_hn[4][32];

    if (tileIdx < ws->T) {
        const int aBase = ws->wl_a[tileIdx];
        const int c     = ws->wl_c[tileIdx];
        const int p     = ((c - 1) ^ 1) + 1;          // confused partner: (1,2)(3,4)(5,6)
        const int posS = ws->S[c], posRealE = posS + ws->n[c];
        const int negS = ws->S[p], negRealE = negS + ws->n[p];
        const int nPosT = (ws->S[c + 1] - posS) >> 4; // padded bucket ends are S[x+1]
        const int nNegT = (ws->S[p + 1] - negS) >> 4;
        const int nTT   = nPosT + nNegT;
        const bool hasPN = (ws->n[c] >= 2) && (ws->n[p] >= 1);

        const unsigned short* ebf = &ws->ebf[0][0];
        const int* __restrict__ idx = ws->idx;

        bf16x8 afrag[2][8];                            // A frags: [m=col][k=quad*8+j]
        #pragma unroll
        for (int t2 = 0; t2 < 2; ++t2) {
            int ar = idx[aBase + t2 * 16 + col];
            const unsigned short* rp = ebf + (size_t)ar * Hdim + quad * 8;
            #pragma unroll
            for (int ks = 0; ks < 8; ++ks)
                afrag[t2][ks] = *(const bf16x8*)(rp + ks * 32);
        }

        float runMin[2][4], runMax[2][4];
        #pragma unroll
        for (int t2 = 0; t2 < 2; ++t2)
            #pragma unroll
            for (int r = 0; r < 4; ++r) { runMin[t2][r] = BIGV; runMax[t2][r] = -BIGV; }

        auto j0Of = [&](int t) -> int {
            return (t < nPosT) ? (posS + (t << 4)) : (negS + ((t - nPosT) << 4));
        };
        bf16x8 b0[8], b1[8];
        auto loadB = [&](bf16x8 (&bf)[8], int t) {
            int jr = idx[j0Of(t) + col];
            const unsigned short* rp = ebf + (size_t)jr * Hdim + quad * 8;
            #pragma unroll
            for (int ks = 0; ks < 8; ++ks)
                bf[ks] = *(const bf16x8*)(rp + ks * 32);
        };
        auto computeT = [&](bf16x8 (&bf)[8], int t) {
            int j0 = j0Of(t);
            bool isPos = t < nPosT;                    // wave-uniform
            int realE  = isPos ? posRealE : negRealE;
            bool valid = (j0 + col) < realE;           // positional mask, 1 v_cmp/tile
            #pragma unroll
            for (int t2 = 0; t2 < 2; ++t2) {
                f32x4 acc = {0.f, 0.f, 0.f, 0.f};
                #pragma unroll
                for (int ks = 0; ks < 8; ++ks)
                    acc = __builtin_amdgcn_mfma_f32_16x16x32_bf16(afrag[t2][ks], bf[ks], acc, 0, 0, 0);
                if (isPos) {                           // self-sim is max => min unaffected (n>=2 gated)
                    #pragma unroll
                    for (int r = 0; r < 4; ++r)
                        runMin[t2][r] = fminf(runMin[t2][r], valid ? acc[r] : BIGV);
                } else {
                    #pragma unroll
                    for (int r = 0; r < 4; ++r)
                        runMax[t2][r] = fmaxf(runMax[t2][r], valid ? acc[r] : -BIGV);
                }
            }
        };

        // 4 waves stride the j-tile list; register double-buffered
        int nIter = (nTT > wave) ? ((nTT - wave + 3) >> 2) : 0;
        int t = wave, i = 0;
        if (nIter > 0) loadB(b0, t);
        while (i + 2 <= nIter) {
            loadB(b1, t + 4);
            computeT(b0, t);
            if (i + 2 < nIter) loadB(b0, t + 8);
            computeT(b1, t + 4);
            t += 8; i += 2;
        }
        if (i < nIter) computeT(b0, t);

        // reduce across 16 cols; col==0 lanes stash per-wave results in LDS
        #pragma unroll
        for (int t2 = 0; t2 < 2; ++t2)
            #pragma unroll
            for (int r = 0; r < 4; ++r) {
                float mn = runMin[t2][r], mx = runMax[t2][r];
                #pragma unroll
                for (int off = 1; off < 16; off <<= 1) {
                    mn = fminf(mn, __shfl_xor(mn, off));
                    mx = fmaxf(mx, __shfl_xor(mx, off));
                }
                if (col == 0) {
                    int a = t2 * 16 + quad * 4 + r;
                    lds_hp[wave][a] = mn;
                    lds_hn[wave][a] = mx;
                }
            }
        __syncthreads();

        // wave 0: combine 4 waves, compute this tile's loss contribution
        if (wave == 0) {
            float contrib = 0.f; int cc = 0;
            if (lane < 32) {
                float hp = fminf(fminf(lds_hp[0][lane], lds_hp[1][lane]),
                                 fminf(lds_hp[2][lane], lds_hp[3][lane]));
                float hn = fmaxf(fmaxf(lds_hn[0][lane], lds_hn[1][lane]),
                                 fmaxf(lds_hn[2][lane], lds_hn[3][lane]));
                bool real = (aBase + lane) < posRealE;
                if (real && hasPN) {
                    float tr = MARGIN + hn - hp;
                    contrib = (tr > 0.f) ? tr : 0.f;
                    cc = 1;
                }
            }
            #pragma unroll
            for (int off = 32; off >= 1; off >>= 1) {
                contrib += __shfl_xor(contrib, off);
                cc      += __shfl_xor(cc, off);
            }
            if (lane == 0) {
                atomicAdd(&ws->wsum, contrib);
                atomicAdd(&ws->wcnt, cc);
            }
        }
    }

    // completion: same thread that issued data atomics drains them (s_waitcnt) first;
    // last block atomic-reads the totals. No threadfence / L2 writeback needed.
    if (threadIdx.x == 0) {
        __builtin_amdgcn_s_waitcnt(0);
        unsigned old = atomicAdd(&ws->done, 1u);
        if (old == (unsigned)(gridDim.x - 1)) {
            float s = atomicAdd(&ws->wsum, 0.0f);   // coherent atomic read
            int   n = atomicAdd(&ws->wcnt, 0);
            out[0] = (n > 0) ? s / (float)n : 0.f;
        }
    }
}

extern "C" void kernel_launch(void* const* d_in, const int* in_sizes, int n_in,
                              void* d_out, int out_size, void* d_ws, size_t ws_size,
                              hipStream_t stream) {
    const float* emb = (const float*)d_in[0];
    const int*   lab = (const int*)d_in[1];
    int N = in_sizes[1];                               // 8192
    WS* ws = (WS*)d_ws;

    prep_kernel<<<1 + (N + 15) / 16, 1024, 0, stream>>>(emb, lab, ws, N);
    sim_kernel<<<WLMAX, 256, 0, stream>>>(ws, (float*)d_out);
}

// Round 5
// 95.051 us; speedup vs baseline: 1.0613x; 1.0236x over previous
//
#include <hip/hip_runtime.h>
#include <math.h>

#define Hdim    256                    // embedding dim
#define NMAX    8192
#define NPADMAX (NMAX + 6 * 32)        // classes 1..6 bucketed, padded to 32
#define WLMAX   264                    // static sim grid: max 32-anchor tiles
#define BIGV    1e9f
#define MARGIN  0.5f

typedef __attribute__((ext_vector_type(8))) short bf16x8;   // MFMA A/B frag
typedef __attribute__((ext_vector_type(4))) float f32x4;    // MFMA C/D frag

struct WS {
    unsigned short ebf[NMAX][Hdim];    // normalized bf16 rows at ORIGINAL row positions
    int idx[NPADMAX];                  // class-bucketed original-row index list (padded to 32)
    int S[8];                          // S[1..6] bucket starts, S[7] = padded end
    int n[8];                          // real bucket counts
    int wl_a[WLMAX];                   // worklist: anchor base (bucketed coords)
    int wl_c[WLMAX];                   // worklist: class
    int T;                             // worklist length
    unsigned done;                     // block completion counter
    float wsum;                        // triplet loss sum
    int   wcnt;                        // triplet count
};

__device__ inline unsigned short f2bf(float f) {    // fp32 -> bf16 RNE
    unsigned u = __float_as_uint(f);
    return (unsigned short)((u + 0x7fffu + ((u >> 16) & 1u)) >> 16);
}

// ---- K1 fused: block 0 = planning (16-wave per-element atomics: hist -> layout ->
//               worklist -> index scatter); blocks 1..512 = per-row L2-normalize ->
//               bf16 at ORIGINAL position (16 rows/block).
//      No data dependency between the two roles (norm keys off lab[] directly), so
//      the single plan block hides under the norm blocks. Measured best config
//      (round 2: 94.1 us): the per-element LDS-atomic plan is fully shadowed by the
//      norm blocks; the "cheaper" ballot counting-sort plan (round 4) measured no
//      better (its tid0 serial section + barrier chain sits on the visible tail),
//      and the 64-anchor sim variant (round 3) regressed on VGPR pressure.
__global__ __launch_bounds__(1024) void prep_kernel(const float* __restrict__ in,
                                                    const int* __restrict__ lab,
                                                    WS* ws, int N) {
    if (blockIdx.x == 0) {
        __shared__ int h[8], S[8], cur[8], ntp[8];
        const int tid = threadIdx.x;
        if (tid < 8) h[tid] = 0;
        __syncthreads();

        // pass 1: histogram, per-element LDS atomics (16 waves hide latency)
        for (int i = tid; i < N; i += 1024) {
            int l = lab[i];
            if (l >= 1 && l <= 6) atomicAdd(&h[l], 1);
        }
        __syncthreads();

        if (tid == 0) {
            int acc = 0, tt = 0;
            #pragma unroll
            for (int c = 1; c <= 6; ++c) {
                S[c]   = acc; acc += ((h[c] + 31) >> 5) << 5;
                ntp[c] = tt;  tt  += (h[c] + 31) >> 5;
            }
            S[0] = 0; S[7] = acc; ntp[0] = 0; ntp[7] = tt;
            ws->T = tt;
            ws->done = 0u; ws->wsum = 0.f; ws->wcnt = 0;
            #pragma unroll
            for (int c = 0; c < 8; ++c) { ws->n[c] = h[c]; ws->S[c] = S[c]; }
        }
        __syncthreads();

        if (tid < 8) cur[tid] = S[tid];
        // worklist, parallel over tiles
        if (tid < ntp[7]) {
            int c = 1;
            while (tid >= ntp[c + 1]) ++c;
            ws->wl_a[tid] = S[c] + ((tid - ntp[c]) << 5);
            ws->wl_c[tid] = c;
        }
        // pad slots -> row 0 (keeps sim addresses in-bounds; masked positionally later)
        if (tid < 192) {
            int c = (tid >> 5) + 1;
            int s = S[c] + h[c] + (tid & 31);
            if (s < S[c + 1]) ws->idx[s] = 0;
        }
        __syncthreads();           // cur[] ready before scatter

        // pass 2: index scatter, per-element LDS atomics (order-invariant result)
        for (int i = tid; i < N; i += 1024) {
            int l = lab[i];
            if (l >= 1 && l <= 6) ws->idx[atomicAdd(&cur[l], 1)] = i;
        }
    } else {
        const int row  = (blockIdx.x - 1) * 16 + (threadIdx.x >> 6);
        const int lane = threadIdx.x & 63;
        if (row >= N) return;
        const int l = lab[row];                // wave-uniform
        if (l < 1 || l > 6) return;            // class not in any confused pair: never read
        float4 v = ((const float4*)(in + (size_t)row * Hdim))[lane];
        float ss = v.x*v.x + v.y*v.y + v.z*v.z + v.w*v.w;
        #pragma unroll
        for (int off = 32; off >= 1; off >>= 1) ss += __shfl_xor(ss, off);
        float sc = 1.0f / fmaxf(sqrtf(ss), 1e-12f);
        ushort4 o;
        o.x = f2bf(v.x * sc); o.y = f2bf(v.y * sc);
        o.z = f2bf(v.z * sc); o.w = f2bf(v.w * sc);
        ((ushort4*)(&ws->ebf[row][0]))[lane] = o;
    }
}

// ---- K2: one block = one 32-anchor tile, full j-sweep via idx indirection;
//          LDS combine; ~3 atomics/block ----
__global__ __launch_bounds__(256) void sim_kernel(WS* ws, float* __restrict__ out) {
    const int wave = threadIdx.x >> 6;
    const int lane = threadIdx.x & 63;
    const int col  = lane & 15;            // C col = j index
    const int quad = lane >> 4;            // C row group
    const int tileIdx = blockIdx.x;

    __shared__ float lds_hp[4][32], lds_hn[4][32];

    if (tileIdx < ws->T) {
        const int aBase = ws->wl_a[tileIdx];
        const int c     = ws->wl_c[tileIdx];
        const int p     = ((c - 1) ^ 1) + 1;          // confused partner: (1,2)(3,4)(5,6)
        const int posS = ws->S[c], posRealE = posS + ws->n[c];
        const int negS = ws->S[p], negRealE = negS + ws->n[p];
        const int nPosT = (ws->S[c + 1] - posS) >> 4; // padded bucket ends are S[x+1]
        const int nNegT = (ws->S[p + 1] - negS) >> 4;
        const int nTT   = nPosT + nNegT;
        const bool hasPN = (ws->n[c] >= 2) && (ws->n[p] >= 1);

        const unsigned short* ebf = &ws->ebf[0][0];
        const int* __restrict__ idx = ws->idx;

        bf16x8 afrag[2][8];                            // A frags: [m=col][k=quad*8+j]
        #pragma unroll
        for (int t2 = 0; t2 < 2; ++t2) {
            int ar = idx[aBase + t2 * 16 + col];
            const unsigned short* rp = ebf + (size_t)ar * Hdim + quad * 8;
            #pragma unroll
            for (int ks = 0; ks < 8; ++ks)
                afrag[t2][ks] = *(const bf16x8*)(rp + ks * 32);
        }

        float runMin[2][4], runMax[2][4];
        #pragma unroll
        for (int t2 = 0; t2 < 2; ++t2)
            #pragma unroll
            for (int r = 0; r < 4; ++r) { runMin[t2][r] = BIGV; runMax[t2][r] = -BIGV; }

        auto j0Of = [&](int t) -> int {
            return (t < nPosT) ? (posS + (t << 4)) : (negS + ((t - nPosT) << 4));
        };
        bf16x8 b0[8], b1[8];
        auto loadB = [&](bf16x8 (&bf)[8], int t) {
            int jr = idx[j0Of(t) + col];
            const unsigned short* rp = ebf + (size_t)jr * Hdim + quad * 8;
            #pragma unroll
            for (int ks = 0; ks < 8; ++ks)
                bf[ks] = *(const bf16x8*)(rp + ks * 32);
        };
        auto computeT = [&](bf16x8 (&bf)[8], int t) {
            int j0 = j0Of(t);
            bool isPos = t < nPosT;                    // wave-uniform
            int realE  = isPos ? posRealE : negRealE;
            bool valid = (j0 + col) < realE;           // positional mask, 1 v_cmp/tile
            #pragma unroll
            for (int t2 = 0; t2 < 2; ++t2) {
                f32x4 acc = {0.f, 0.f, 0.f, 0.f};
                #pragma unroll
                for (int ks = 0; ks < 8; ++ks)
                    acc = __builtin_amdgcn_mfma_f32_16x16x32_bf16(afrag[t2][ks], bf[ks], acc, 0, 0, 0);
                if (isPos) {                           // self-sim is max => min unaffected (n>=2 gated)
                    #pragma unroll
                    for (int r = 0; r < 4; ++r)
                        runMin[t2][r] = fminf(runMin[t2][r], valid ? acc[r] : BIGV);
                } else {
                    #pragma unroll
                    for (int r = 0; r < 4; ++r)
                        runMax[t2][r] = fmaxf(runMax[t2][r], valid ? acc[r] : -BIGV);
                }
            }
        };

        // 4 waves stride the j-tile list; register double-buffered
        int nIter = (nTT > wave) ? ((nTT - wave + 3) >> 2) : 0;
        int t = wave, i = 0;
        if (nIter > 0) loadB(b0, t);
        while (i + 2 <= nIter) {
            loadB(b1, t + 4);
            computeT(b0, t);
            if (i + 2 < nIter) loadB(b0, t + 8);
            computeT(b1, t + 4);
            t += 8; i += 2;
        }
        if (i < nIter) computeT(b0, t);

        // reduce across 16 cols; col==0 lanes stash per-wave results in LDS
        #pragma unroll
        for (int t2 = 0; t2 < 2; ++t2)
            #pragma unroll
            for (int r = 0; r < 4; ++r) {
                float mn = runMin[t2][r], mx = runMax[t2][r];
                #pragma unroll
                for (int off = 1; off < 16; off <<= 1) {
                    mn = fminf(mn, __shfl_xor(mn, off));
                    mx = fmaxf(mx, __shfl_xor(mx, off));
                }
                if (col == 0) {
                    int a = t2 * 16 + quad * 4 + r;
                    lds_hp[wave][a] = mn;
                    lds_hn[wave][a] = mx;
                }
            }
        __syncthreads();

        // wave 0: combine 4 waves, compute this tile's loss contribution
        if (wave == 0) {
            float contrib = 0.f; int cc = 0;
            if (lane < 32) {
                float hp = fminf(fminf(lds_hp[0][lane], lds_hp[1][lane]),
                                 fminf(lds_hp[2][lane], lds_hp[3][lane]));
                float hn = fmaxf(fmaxf(lds_hn[0][lane], lds_hn[1][lane]),
                                 fmaxf(lds_hn[2][lane], lds_hn[3][lane]));
                bool real = (aBase + lane) < posRealE;
                if (real && hasPN) {
                    float tr = MARGIN + hn - hp;
                    contrib = (tr > 0.f) ? tr : 0.f;
                    cc = 1;
                }
            }
            #pragma unroll
            for (int off = 32; off >= 1; off >>= 1) {
                contrib += __shfl_xor(contrib, off);
                cc      += __shfl_xor(cc, off);
            }
            if (lane == 0) {
                atomicAdd(&ws->wsum, contrib);
                atomicAdd(&ws->wcnt, cc);
            }
        }
    }

    // completion: same thread that issued data atomics drains them (s_waitcnt) first;
    // last block atomic-reads the totals. No threadfence / L2 writeback needed.
    if (threadIdx.x == 0) {
        __builtin_amdgcn_s_waitcnt(0);
        unsigned old = atomicAdd(&ws->done, 1u);
        if (old == (unsigned)(gridDim.x - 1)) {
            float s = atomicAdd(&ws->wsum, 0.0f);   // coherent atomic read
            int   n = atomicAdd(&ws->wcnt, 0);
            out[0] = (n > 0) ? s / (float)n : 0.f;
        }
    }
}

extern "C" void kernel_launch(void* const* d_in, const int* in_sizes, int n_in,
                              void* d_out, int out_size, void* d_ws, size_t ws_size,
                              hipStream_t stream) {
    const float* emb = (const float*)d_in[0];
    const int*   lab = (const int*)d_in[1];
    int N = in_sizes[1];                               // 8192
    WS* ws = (WS*)d_ws;

    prep_kernel<<<1 + (N + 15) / 16, 1024, 0, stream>>>(emb, lab, ws, N);
    sim_kernel<<<WLMAX, 256, 0, stream>>>(ws, (float*)d_out);
}